// Round 2
// baseline (129.345 us; speedup 1.0000x reference)
//
#include <hip/hip_runtime.h>
#include <hip/hip_bf16.h>

// out[t,z] = sum_{i,j} f[t,i] * a[t,j] * C[i,j,z]
// GEMM M=4096(t) N=128(z) K=16384(i*128+j), A generated on the fly.
// Grid 256 = 32 Mtiles * 4 z-slices * 2 k-halves; block 512 thr (8 waves).
// bid&7 = (slice) -> XCD-affine so each XCD L2 caches its 1MiB C slice.

typedef __attribute__((ext_vector_type(8))) short bf16x8;
typedef __attribute__((ext_vector_type(4))) float f32x4;

__device__ __forceinline__ unsigned pkbf16(float x, float y) {
    __hip_bfloat162 h = __float22bfloat162_rn(make_float2(x, y));
    unsigned u;
    __builtin_memcpy(&u, &h, sizeof(u));   // bit_cast rejected: type not trivially copyable
    return u;
}

__global__ __launch_bounds__(512) void cooc_gemm(
    const float* __restrict__ fa, const float* __restrict__ Cc,
    float* __restrict__ out)
{
    __shared__ float  f_lds[128 * 68];      // f[t][i_local], stride 68 (pad, 16B-aligned rows)
    __shared__ ushort bT[2][32 * 128];      // double-buffered transposed+swizzled bf16 C slab

    const int bid   = blockIdx.x;
    const int nsl   = (bid & 7) >> 1;       // z-slice 0..3
    const int khalf = bid & 1;              // i-half 0..1
    const int mtile = bid >> 3;             // 0..31
    const int t0 = mtile * 128;
    const int z0 = nsl * 32;
    const int i0 = khalf * 64;

    const int tid  = threadIdx.x;
    const int lane = tid & 63;
    const int wave = tid >> 6;
    const int wt = wave >> 1;               // 0..3 : token subtile (32 rows)
    const int wz = wave & 1;                // 0..1 : z subtile (16 cols)
    const int lm = lane & 15;
    const int lk = lane >> 4;               // 0..3 : k-group within MFMA

    // ---- stage f tile: f[t0+tt][i0..i0+64) into LDS (coalesced) ----
    {
        int tt = tid >> 4;
        const int il = (tid & 15) * 4;
        #pragma unroll
        for (int rep = 0; rep < 4; ++rep, tt += 32) {
            float4 v = *(const float4*)(fa + (size_t)(t0 + tt) * 256 + i0 + il);
            *(float4*)(f_lds + tt * 68 + il) = v;
        }
    }

    // ---- cache a-fragments in registers (slab-invariant): a[row][j] fp32 ----
    // A-frag layout (16x16x32): row m = lane&15, k = (lane>>4)*8 + e
    float4 a_cache[2][4][2];   // [msub][kstep][half of 8 floats]
    #pragma unroll
    for (int ms = 0; ms < 2; ++ms) {
        const int row = t0 + wt * 32 + ms * 16 + lm;
        const float* ab = fa + (size_t)row * 256 + 128;
        #pragma unroll
        for (int ks = 0; ks < 4; ++ks) {
            a_cache[ms][ks][0] = *(const float4*)(ab + ks * 32 + lk * 8);
            a_cache[ms][ks][1] = *(const float4*)(ab + ks * 32 + lk * 8 + 4);
        }
    }

    // ---- C slab staging: waves 0-3 each transpose a 4x4 block per pass ----
    const bool stager = (wave < 4);
    const int zb = tid & 7;                 // z-quad 0..7  (covers 32 z)
    const int jb = (tid >> 3) & 31;         // j-quad 0..31 (covers 128 j)
    const float* csrc0 = Cc + (size_t)i0 * 16384 + (size_t)(jb * 4) * 128 + z0 + zb * 4;

    union { float4 v4[4]; float f[16]; } La;

    auto do_loads = [&](int s_next) {
        const float* p = csrc0 + (size_t)s_next * 16384;
        #pragma unroll
        for (int r = 0; r < 4; ++r)
            La.v4[r] = *(const float4*)(p + r * 128);   // coalesced: lanes sweep z,j
    };
    auto do_write = [&](int b) {
        #pragma unroll
        for (int rr = 0; rr < 4; ++rr) {
            const int zloc = zb * 4 + rr;
            const unsigned lo = pkbf16(La.f[0 * 4 + rr], La.f[1 * 4 + rr]);
            const unsigned hi = pkbf16(La.f[2 * 4 + rr], La.f[3 * 4 + rr]);
            // 16B-granule XOR swizzle: granule g = j>>3, stored at g ^ (z&15)
            const int off = zloc * 128 + (((jb >> 1) ^ (zloc & 15)) << 3) + (jb & 1) * 4;
            *(uint2*)(&bT[b][off]) = make_uint2(lo, hi);   // 2-way banks: free
        }
    };

    if (stager) { do_loads(0); do_write(0); }
    __syncthreads();

    f32x4 acc0 = {0.f, 0.f, 0.f, 0.f};
    f32x4 acc1 = {0.f, 0.f, 0.f, 0.f};

    const int frow0 = (wt * 32 + lm) * 68;
    const int frow1 = (wt * 32 + 16 + lm) * 68;
    const int zz = wz * 16 + lm;            // B-operand n-col (z local)

    #pragma unroll 2
    for (int s = 0; s < 64; ++s) {
        const int buf = s & 1;
        if (stager && s < 63) do_loads(s + 1);   // prefetch next slab into regs

        const float fs0 = f_lds[frow0 + s];      // f[row][i]  (broadcast reads, conflict-free)
        const float fs1 = f_lds[frow1 + s];

        #pragma unroll
        for (int ks = 0; ks < 4; ++ks) {
            // B-frag: k = j = ks*32 + lk*8 + e, n = zz ; swizzled b128 read (full BW)
            const int boff = zz * 128 + ((((ks * 4) + lk) ^ lm) << 3);
            bf16x8 bfrag = *(const bf16x8*)(&bT[buf][boff]);

            union { unsigned u[4]; bf16x8 v; } A0, A1;
            {
                const float4 q0 = a_cache[0][ks][0], q1 = a_cache[0][ks][1];
                A0.u[0] = pkbf16(q0.x * fs0, q0.y * fs0);
                A0.u[1] = pkbf16(q0.z * fs0, q0.w * fs0);
                A0.u[2] = pkbf16(q1.x * fs0, q1.y * fs0);
                A0.u[3] = pkbf16(q1.z * fs0, q1.w * fs0);
            }
            {
                const float4 q0 = a_cache[1][ks][0], q1 = a_cache[1][ks][1];
                A1.u[0] = pkbf16(q0.x * fs1, q0.y * fs1);
                A1.u[1] = pkbf16(q0.z * fs1, q0.w * fs1);
                A1.u[2] = pkbf16(q1.x * fs1, q1.y * fs1);
                A1.u[3] = pkbf16(q1.z * fs1, q1.w * fs1);
            }
            acc0 = __builtin_amdgcn_mfma_f32_16x16x32_bf16(A0.v, bfrag, acc0, 0, 0, 0);
            acc1 = __builtin_amdgcn_mfma_f32_16x16x32_bf16(A1.v, bfrag, acc1, 0, 0, 0);
        }

        if (stager && s < 63) do_write(buf ^ 1); // write next slab to other buffer
        __syncthreads();
    }

    // ---- epilogue: C/D layout col = lane&15, row = (lane>>4)*4 + reg ----
    const int col = z0 + zz;
    #pragma unroll
    for (int r = 0; r < 4; ++r) {
        const int row0 = t0 + wt * 32 + lk * 4 + r;
        atomicAdd(out + (size_t)row0 * 128 + col, acc0[r]);
        atomicAdd(out + (size_t)(row0 + 16) * 128 + col, acc1[r]);
    }
}

extern "C" void kernel_launch(void* const* d_in, const int* in_sizes, int n_in,
                              void* d_out, int out_size, void* d_ws, size_t ws_size,
                              hipStream_t stream) {
    const float* fa = (const float*)d_in[0];   // (4096, 256) fp32: [:,0:128]=f, [:,128:256]=a
    const float* Cc = (const float*)d_in[1];   // (128,128,128) fp32
    float* out = (float*)d_out;                // (4096, 128) fp32
    (void)hipMemsetAsync(out, 0, (size_t)out_size * sizeof(float), stream);
    cooc_gemm<<<256, 512, 0, stream>>>(fa, Cc, out);
}